// Round 10
// baseline (600.765 us; speedup 1.0000x reference)
//
#include <hip/hip_runtime.h>

#define N_NODES   50000
#define N_EDGES   800000
#define IN_CH     128
#define HID       64
#define OUT_CH    64
#define N_CLASSES 10
#define N_GRAPHS  256

// ---------------- int degree histogram ----------------
__global__ __launch_bounds__(256) void deg_kernel(const int* __restrict__ ei,
                                                  int* __restrict__ cnt) {
    int e = blockIdx.x * 256 + threadIdx.x;
    if (e >= N_EDGES) return;
    atomicAdd(&cnt[ei[N_EDGES + e]], 1);
}

// ---------------- scan phase 1: per-block exclusive scan + block totals ----------------
__global__ __launch_bounds__(256) void scan1_kernel(const int* __restrict__ cnt,
                                                    int* __restrict__ excl,
                                                    int* __restrict__ part) {
    __shared__ int s[256];
    int t = threadIdx.x, i = blockIdx.x * 256 + t;
    int v = (i < N_NODES) ? cnt[i] : 0;
    s[t] = v; __syncthreads();
    for (int off = 1; off < 256; off <<= 1) {
        int x = (t >= off) ? s[t - off] : 0;
        __syncthreads();
        s[t] += x;
        __syncthreads();
    }
    if (i < N_NODES) excl[i] = s[t] - v;
    if (t == 255) part[blockIdx.x] = s[t];
}

// ---------------- scan phase 2 (fused): redundant part-scan + rs/cur/dinv + bounds ----------
// Each block scans the 196 block totals in LDS, applies its prefix; also emits
// graph-boundary table start[] (batch is sorted) and dinv.
__global__ __launch_bounds__(256) void scan3_kernel(const int* __restrict__ excl,
                                                    const int* __restrict__ part,
                                                    const int* __restrict__ cnt,
                                                    const int* __restrict__ batch,
                                                    int* __restrict__ rs,
                                                    int* __restrict__ cur,
                                                    float* __restrict__ dinv,
                                                    int* __restrict__ start,
                                                    int nblk) {
    __shared__ int pp[256];
    int t = threadIdx.x;
    pp[t] = (t < nblk) ? part[t] : 0;
    __syncthreads();
    for (int off = 1; off < 256; off <<= 1) {
        int x = (t >= off) ? pp[t - off] : 0;
        __syncthreads();
        pp[t] += x;
        __syncthreads();
    }
    int pref = (blockIdx.x == 0) ? 0 : pp[blockIdx.x - 1];

    int i = blockIdx.x * 256 + t;
    if (i < N_NODES) {
        int v = excl[i] + pref;
        rs[i]  = v;
        cur[i] = v;
        dinv[i] = rsqrtf((float)cnt[i] + 1.0f);
        // graph boundaries
        int c = batch[i];
        int p = (i == 0) ? -1 : batch[i - 1];
        for (int g = p + 1; g <= c; ++g) start[g] = i;
        if (i == N_NODES - 1)
            for (int g = c + 1; g <= N_GRAPHS; ++g) start[g] = N_NODES;
    } else if (i == N_NODES) {
        rs[N_NODES] = N_EDGES;
    }
}

// ---------------- bucket edges into dst-CSR: pack src only (4 B) ----------------
__global__ __launch_bounds__(256) void bucket_kernel(const int* __restrict__ ei,
                                                     int* __restrict__ cur,
                                                     int* __restrict__ pack) {
    int e = blockIdx.x * 256 + threadIdx.x;
    if (e >= N_EDGES) return;
    int s = ei[e];
    int d = ei[N_EDGES + e];
    int pos = atomicAdd(&cur[d], 1);
    pack[pos] = s;
}

// ---------------- GEMM1: hs1 = (x @ W1) * dinv ----------------
// 32-row tile; thread = 2 nodes x 4 cols; k-unrolled x4 with float4 LDS reads.
__global__ __launch_bounds__(256) void gemm1_kernel(
    const float* __restrict__ X, const float* __restrict__ W,
    const float* __restrict__ dinv, float* __restrict__ hs) {
    __shared__ float xs[32][IN_CH + 4];   // row stride 132 floats = 528 B (16B aligned)
    __shared__ float ws[IN_CH][64];
    const int tid = threadIdx.x;
    const int base = blockIdx.x * 32;

    for (int i = tid; i < IN_CH * 64; i += 256) (&ws[0][0])[i] = W[i];
    for (int i = tid; i < 32 * IN_CH; i += 256) {
        int r = i >> 7, k = i & 127;
        int n = base + r;
        xs[r][k] = (n < N_NODES) ? X[(size_t)n * IN_CH + k] : 0.0f;
    }
    __syncthreads();

    const int sub = tid >> 4;            // 0..15
    const int c0  = (tid & 15) * 4;
    float a0 = 0.f, a1 = 0.f, a2 = 0.f, a3 = 0.f;
    float b0 = 0.f, b1_ = 0.f, b2_ = 0.f, b3 = 0.f;
#pragma unroll
    for (int k = 0; k < IN_CH; k += 4) {
        float4 xa = *reinterpret_cast<const float4*>(&xs[sub][k]);
        float4 xb = *reinterpret_cast<const float4*>(&xs[sub + 16][k]);
        float4 w0 = *reinterpret_cast<const float4*>(&ws[k][c0]);
        float4 w1 = *reinterpret_cast<const float4*>(&ws[k + 1][c0]);
        float4 w2 = *reinterpret_cast<const float4*>(&ws[k + 2][c0]);
        float4 w3 = *reinterpret_cast<const float4*>(&ws[k + 3][c0]);
        a0 += xa.x * w0.x + xa.y * w1.x + xa.z * w2.x + xa.w * w3.x;
        a1 += xa.x * w0.y + xa.y * w1.y + xa.z * w2.y + xa.w * w3.y;
        a2 += xa.x * w0.z + xa.y * w1.z + xa.z * w2.z + xa.w * w3.z;
        a3 += xa.x * w0.w + xa.y * w1.w + xa.z * w2.w + xa.w * w3.w;
        b0 += xb.x * w0.x + xb.y * w1.x + xb.z * w2.x + xb.w * w3.x;
        b1_ += xb.x * w0.y + xb.y * w1.y + xb.z * w2.y + xb.w * w3.y;
        b2_ += xb.x * w0.z + xb.y * w1.z + xb.z * w2.z + xb.w * w3.z;
        b3 += xb.x * w0.w + xb.y * w1.w + xb.z * w2.w + xb.w * w3.w;
    }
    int na = base + sub, nb = base + sub + 16;
    if (na < N_NODES) {
        float di = dinv[na];
        *reinterpret_cast<float4*>(&hs[(size_t)na * 64 + c0]) =
            make_float4(a0 * di, a1 * di, a2 * di, a3 * di);
    }
    if (nb < N_NODES) {
        float di = dinv[nb];
        *reinterpret_cast<float4*>(&hs[(size_t)nb * 64 + c0]) =
            make_float4(b0 * di, b1_ * di, b2_ * di, b3 * di);
    }
}

// ---------------- fused gather1 + GEMM2 ----------------
// stage: xs[r] = relu(dinv[n]*(hs1[n] + sum_{src in CSR(n)} hs1[src]) + b1)
// then:  hs2 = (xs @ W2) * dinv
__global__ __launch_bounds__(256) void gemmgather2_kernel(
    const int* __restrict__ rs, const int* __restrict__ pack,
    const float* __restrict__ hs1, const float* __restrict__ dinv,
    const float* __restrict__ W2, const float* __restrict__ b1,
    float* __restrict__ hs2) {
    __shared__ float xs[16][64];
    __shared__ float ws[64][64];
    const int tid  = threadIdx.x;
    const int base = blockIdx.x * 16;
    const int wave = tid >> 6;
    const int lane = tid & 63;

    for (int i = tid; i < 64 * 64; i += 256) (&ws[0][0])[i] = W2[i];

    const float bb = b1[lane];
    for (int r = wave * 4; r < wave * 4 + 4; ++r) {
        int n = base + r;
        float own = hs1[(size_t)n * 64 + lane];
        float di  = dinv[n];
        int e = rs[n], end = rs[n + 1];
        float acc = 0.f;
        for (; e + 7 < end; e += 8) {
            int s0 = pack[e],     s1 = pack[e + 1], s2 = pack[e + 2], s3 = pack[e + 3];
            int s4 = pack[e + 4], s5 = pack[e + 5], s6 = pack[e + 6], s7 = pack[e + 7];
            float h0 = hs1[(size_t)s0 * 64 + lane];
            float h1 = hs1[(size_t)s1 * 64 + lane];
            float h2 = hs1[(size_t)s2 * 64 + lane];
            float h3 = hs1[(size_t)s3 * 64 + lane];
            float h4 = hs1[(size_t)s4 * 64 + lane];
            float h5 = hs1[(size_t)s5 * 64 + lane];
            float h6 = hs1[(size_t)s6 * 64 + lane];
            float h7 = hs1[(size_t)s7 * 64 + lane];
            acc += ((h0 + h1) + (h2 + h3)) + ((h4 + h5) + (h6 + h7));
        }
        for (; e + 3 < end; e += 4) {
            int s0 = pack[e], s1 = pack[e + 1], s2 = pack[e + 2], s3 = pack[e + 3];
            float h0 = hs1[(size_t)s0 * 64 + lane];
            float h1 = hs1[(size_t)s1 * 64 + lane];
            float h2 = hs1[(size_t)s2 * 64 + lane];
            float h3 = hs1[(size_t)s3 * 64 + lane];
            acc += (h0 + h1) + (h2 + h3);
        }
        for (; e < end; ++e)
            acc += hs1[(size_t)pack[e] * 64 + lane];
        xs[r][lane] = fmaxf(di * (own + acc) + bb, 0.f);
    }
    __syncthreads();

    const int sub = tid >> 4;
    const int c0  = (tid & 15) * 4;
    const int n   = base + sub;
    float a0 = 0.f, a1 = 0.f, a2 = 0.f, a3 = 0.f;
#pragma unroll
    for (int k = 0; k < 64; k += 4) {
        float4 xv = *reinterpret_cast<const float4*>(&xs[sub][k]);
        float4 w0 = *reinterpret_cast<const float4*>(&ws[k][c0]);
        float4 w1 = *reinterpret_cast<const float4*>(&ws[k + 1][c0]);
        float4 w2 = *reinterpret_cast<const float4*>(&ws[k + 2][c0]);
        float4 w3 = *reinterpret_cast<const float4*>(&ws[k + 3][c0]);
        a0 += xv.x * w0.x + xv.y * w1.x + xv.z * w2.x + xv.w * w3.x;
        a1 += xv.x * w0.y + xv.y * w1.y + xv.z * w2.y + xv.w * w3.y;
        a2 += xv.x * w0.z + xv.y * w1.z + xv.z * w2.z + xv.w * w3.z;
        a3 += xv.x * w0.w + xv.y * w1.w + xv.z * w2.w + xv.w * w3.w;
    }
    float di = dinv[n];
    *reinterpret_cast<float4*>(&hs2[(size_t)n * 64 + c0]) =
        make_float4(a0 * di, a1 * di, a2 * di, a3 * di);
}

// ---------------- fused gather2 + mean-pool accumulate ----------------
// 4 nodes per wave (grid 3125 blocks) for latency hiding.
__global__ __launch_bounds__(256) void gatherpool_kernel(
    const int* __restrict__ rs, const int* __restrict__ pack,
    const float* __restrict__ hs2, const float* __restrict__ dinv,
    const float* __restrict__ b2, const int* __restrict__ batch,
    float* __restrict__ pooled) {
    int wave = threadIdx.x >> 6;
    int lane = threadIdx.x & 63;
    int base = blockIdx.x * 16 + wave * 4;
    if (base >= N_NODES) return;
    int endn = base + 4;
    if (endn > N_NODES) endn = N_NODES;
    const float bb = b2[lane];
    int curg = batch[base];
    float racc = 0.f;
    for (int n = base; n < endn; ++n) {
        float own = hs2[(size_t)n * 64 + lane];
        float di  = dinv[n];
        int e = rs[n], end = rs[n + 1];
        float acc = 0.f;
        for (; e + 7 < end; e += 8) {
            int s0 = pack[e],     s1 = pack[e + 1], s2 = pack[e + 2], s3 = pack[e + 3];
            int s4 = pack[e + 4], s5 = pack[e + 5], s6 = pack[e + 6], s7 = pack[e + 7];
            float h0 = hs2[(size_t)s0 * 64 + lane];
            float h1 = hs2[(size_t)s1 * 64 + lane];
            float h2 = hs2[(size_t)s2 * 64 + lane];
            float h3 = hs2[(size_t)s3 * 64 + lane];
            float h4 = hs2[(size_t)s4 * 64 + lane];
            float h5 = hs2[(size_t)s5 * 64 + lane];
            float h6 = hs2[(size_t)s6 * 64 + lane];
            float h7 = hs2[(size_t)s7 * 64 + lane];
            acc += ((h0 + h1) + (h2 + h3)) + ((h4 + h5) + (h6 + h7));
        }
        for (; e + 3 < end; e += 4) {
            int s0 = pack[e], s1 = pack[e + 1], s2 = pack[e + 2], s3 = pack[e + 3];
            float h0 = hs2[(size_t)s0 * 64 + lane];
            float h1 = hs2[(size_t)s1 * 64 + lane];
            float h2 = hs2[(size_t)s2 * 64 + lane];
            float h3 = hs2[(size_t)s3 * 64 + lane];
            acc += (h0 + h1) + (h2 + h3);
        }
        for (; e < end; ++e)
            acc += hs2[(size_t)pack[e] * 64 + lane];
        float val = di * (own + acc) + bb;
        int g = batch[n];
        if (g != curg) {
            atomicAdd(&pooled[curg * 64 + lane], racc);
            racc = 0.f;
            curg = g;
        }
        racc += val;
    }
    atomicAdd(&pooled[curg * 64 + lane], racc);
}

// ---------------- head: (pooled/count) @ Wl + bl ----------------
__global__ __launch_bounds__(256) void head_kernel(const float* __restrict__ pooled,
                                                   const int* __restrict__ start,
                                                   const float* __restrict__ Wl,
                                                   const float* __restrict__ bl,
                                                   float* __restrict__ out) {
    int gid = blockIdx.x * 256 + threadIdx.x;
    if (gid >= N_GRAPHS * N_CLASSES) return;
    int g = gid / N_CLASSES, c = gid % N_CLASSES;
    float cntf = (float)(start[g + 1] - start[g]);
    float inv = 1.0f / fmaxf(cntf, 1.0f);
    float acc = 0.f;
#pragma unroll
    for (int k = 0; k < OUT_CH; ++k)
        acc += pooled[g * 64 + k] * Wl[k * N_CLASSES + c];
    out[gid] = acc * inv + bl[c];
}

// ---------------- launch ----------------
extern "C" void kernel_launch(void* const* d_in, const int* in_sizes, int n_in,
                              void* d_out, int out_size, void* d_ws, size_t ws_size,
                              hipStream_t stream) {
    const float* x     = (const float*)d_in[0];
    const int*   ei    = (const int*)d_in[1];
    const int*   batch = (const int*)d_in[3];
    const float* W1    = (const float*)d_in[4];
    const float* b1    = (const float*)d_in[5];
    const float* W2    = (const float*)d_in[6];
    const float* b2    = (const float*)d_in[7];
    const float* Wl    = (const float*)d_in[8];
    const float* bl    = (const float*)d_in[9];
    float* out = (float*)d_out;

    // workspace layout (4-byte units)
    int*   wsI    = (int*)d_ws;
    int*   cnt    = wsI;                         // [0, 50048)  zeroed
    float* pooled = (float*)(wsI + 50048);       // [50048, 66432) zeroed
    int*   start  = wsI + 66432;                 // [66432, 66689)
    float* dinv   = (float*)(wsI + 66752);       // [66752, 116800)
    int*   excl   = wsI + 116800;                // [116800, 166848)
    int*   part   = wsI + 166848;                // [166848, 167104)
    int*   rs     = wsI + 167104;                // [167104, 217168) N_NODES+1
    int*   cur    = wsI + 217168;                // [217168, 267216)
    int*   pack   = wsI + 267216;                // [267216, 1067216) 800000 ints
    float* hs1    = (float*)(wsI + 1067216);     // 3.2M floats
    float* hs2    = (float*)(wsI + 4267216);     // 3.2M floats

    const int NBLK = (N_NODES + 255) / 256;      // 196

    // zero cnt + pooled
    hipMemsetAsync(wsI, 0, (size_t)66432 * sizeof(int), stream);

    // degree + CSR build (same work every call)
    deg_kernel   <<<(N_EDGES + 255) / 256, 256, 0, stream>>>(ei, cnt);
    scan1_kernel <<<NBLK, 256, 0, stream>>>(cnt, excl, part);
    scan3_kernel <<<NBLK, 256, 0, stream>>>(excl, part, cnt, batch,
                                            rs, cur, dinv, start, NBLK);
    bucket_kernel<<<(N_EDGES + 255) / 256, 256, 0, stream>>>(ei, cur, pack);

    // layer 1 GEMM (hs1 = x@W1 * dinv), 32-row tiles
    gemm1_kernel<<<(N_NODES + 31) / 32, 256, 0, stream>>>(x, W1, dinv, hs1);

    // layer 1 gather fused into layer 2 GEMM (hs2 = relu(agg1)@W2 * dinv)
    gemmgather2_kernel<<<N_NODES / 16, 256, 0, stream>>>(
        rs, pack, hs1, dinv, W2, b1, hs2);

    // layer 2 gather fused with mean-pool accumulation (4 nodes/wave)
    gatherpool_kernel<<<(N_NODES + 15) / 16, 256, 0, stream>>>(
        rs, pack, hs2, dinv, b2, batch, pooled);

    // head
    head_kernel<<<(N_GRAPHS * N_CLASSES + 255) / 256, 256, 0, stream>>>(
        pooled, start, Wl, bl, out);
}

// Round 11
// 320.790 us; speedup vs baseline: 1.8728x; 1.8728x over previous
//
#include <hip/hip_runtime.h>

#define N_NODES   50000
#define N_EDGES   800000
#define IN_CH     128
#define HID       64
#define OUT_CH    64
#define N_CLASSES 10
#define N_GRAPHS  256

// ---------------- int degree histogram ----------------
__global__ __launch_bounds__(256) void deg_kernel(const int* __restrict__ ei,
                                                  int* __restrict__ cnt) {
    int e = blockIdx.x * 256 + threadIdx.x;
    if (e >= N_EDGES) return;
    atomicAdd(&cnt[ei[N_EDGES + e]], 1);
}

// ---------------- scan phase 1: per-block exclusive scan + block totals ----------------
__global__ __launch_bounds__(256) void scan1_kernel(const int* __restrict__ cnt,
                                                    int* __restrict__ excl,
                                                    int* __restrict__ part) {
    __shared__ int s[256];
    int t = threadIdx.x, i = blockIdx.x * 256 + t;
    int v = (i < N_NODES) ? cnt[i] : 0;
    s[t] = v; __syncthreads();
    for (int off = 1; off < 256; off <<= 1) {
        int x = (t >= off) ? s[t - off] : 0;
        __syncthreads();
        s[t] += x;
        __syncthreads();
    }
    if (i < N_NODES) excl[i] = s[t] - v;
    if (t == 255) part[blockIdx.x] = s[t];
}

// ---------------- scan phase 2 (fused): redundant part-scan + rs/cur/dinv + bounds ----------
__global__ __launch_bounds__(256) void scan3_kernel(const int* __restrict__ excl,
                                                    const int* __restrict__ part,
                                                    const int* __restrict__ cnt,
                                                    const int* __restrict__ batch,
                                                    int* __restrict__ rs,
                                                    int* __restrict__ cur,
                                                    float* __restrict__ dinv,
                                                    int* __restrict__ start,
                                                    int nblk) {
    __shared__ int pp[256];
    int t = threadIdx.x;
    pp[t] = (t < nblk) ? part[t] : 0;
    __syncthreads();
    for (int off = 1; off < 256; off <<= 1) {
        int x = (t >= off) ? pp[t - off] : 0;
        __syncthreads();
        pp[t] += x;
        __syncthreads();
    }
    int pref = (blockIdx.x == 0) ? 0 : pp[blockIdx.x - 1];

    int i = blockIdx.x * 256 + t;
    if (i < N_NODES) {
        int v = excl[i] + pref;
        rs[i]  = v;
        cur[i] = v;
        dinv[i] = rsqrtf((float)cnt[i] + 1.0f);
        int c = batch[i];
        int p = (i == 0) ? -1 : batch[i - 1];
        for (int g = p + 1; g <= c; ++g) start[g] = i;
        if (i == N_NODES - 1)
            for (int g = c + 1; g <= N_GRAPHS; ++g) start[g] = N_NODES;
    } else if (i == N_NODES) {
        rs[N_NODES] = N_EDGES;
    }
}

// ---------------- bucket edges into dst-CSR: pack src only (4 B) ----------------
__global__ __launch_bounds__(256) void bucket_kernel(const int* __restrict__ ei,
                                                     int* __restrict__ cur,
                                                     int* __restrict__ pack) {
    int e = blockIdx.x * 256 + threadIdx.x;
    if (e >= N_EDGES) return;
    int s = ei[e];
    int d = ei[N_EDGES + e];
    int pos = atomicAdd(&cur[d], 1);
    pack[pos] = s;
}

// ---------------- GEMM1: hs1 = (x @ W1) * dinv  (round-7 proven version) ----------------
__global__ __launch_bounds__(256) void gemm1_kernel(
    const float* __restrict__ X, const float* __restrict__ W,
    const float* __restrict__ dinv, float* __restrict__ hs) {
    __shared__ float xs[16][IN_CH + 1];
    __shared__ float ws[IN_CH][64];
    const int tid = threadIdx.x;
    const int base = blockIdx.x * 16;

    for (int i = tid; i < IN_CH * 64; i += 256) (&ws[0][0])[i] = W[i];
    for (int i = tid; i < 16 * IN_CH; i += 256) {
        int r = i / IN_CH, k = i % IN_CH;
        xs[r][k] = X[(size_t)(base + r) * IN_CH + k];
    }
    __syncthreads();

    const int sub = tid >> 4;
    const int c0  = (tid & 15) * 4;
    const int n   = base + sub;
    float a0 = 0.f, a1 = 0.f, a2 = 0.f, a3 = 0.f;
#pragma unroll 16
    for (int k = 0; k < IN_CH; ++k) {
        float xv  = xs[sub][k];
        float4 wv = *reinterpret_cast<const float4*>(&ws[k][c0]);
        a0 += xv * wv.x; a1 += xv * wv.y; a2 += xv * wv.z; a3 += xv * wv.w;
    }
    float di = dinv[n];
    *reinterpret_cast<float4*>(&hs[(size_t)n * 64 + c0]) =
        make_float4(a0 * di, a1 * di, a2 * di, a3 * di);
}

// ---------------- fused gather1 + GEMM2 ----------------
__global__ __launch_bounds__(256) void gemmgather2_kernel(
    const int* __restrict__ rs, const int* __restrict__ pack,
    const float* __restrict__ hs1, const float* __restrict__ dinv,
    const float* __restrict__ W2, const float* __restrict__ b1,
    float* __restrict__ hs2) {
    __shared__ float xs[16][64];
    __shared__ float ws[64][64];
    const int tid  = threadIdx.x;
    const int base = blockIdx.x * 16;
    const int wave = tid >> 6;
    const int lane = tid & 63;

    for (int i = tid; i < 64 * 64; i += 256) (&ws[0][0])[i] = W2[i];

    const float bb = b1[lane];
    for (int r = wave * 4; r < wave * 4 + 4; ++r) {
        int n = base + r;
        float own = hs1[(size_t)n * 64 + lane];
        float di  = dinv[n];
        int e = rs[n], end = rs[n + 1];
        float acc = 0.f;
        for (; e + 7 < end; e += 8) {
            int s0 = pack[e],     s1 = pack[e + 1], s2 = pack[e + 2], s3 = pack[e + 3];
            int s4 = pack[e + 4], s5 = pack[e + 5], s6 = pack[e + 6], s7 = pack[e + 7];
            float h0 = hs1[(size_t)s0 * 64 + lane];
            float h1 = hs1[(size_t)s1 * 64 + lane];
            float h2 = hs1[(size_t)s2 * 64 + lane];
            float h3 = hs1[(size_t)s3 * 64 + lane];
            float h4 = hs1[(size_t)s4 * 64 + lane];
            float h5 = hs1[(size_t)s5 * 64 + lane];
            float h6 = hs1[(size_t)s6 * 64 + lane];
            float h7 = hs1[(size_t)s7 * 64 + lane];
            acc += ((h0 + h1) + (h2 + h3)) + ((h4 + h5) + (h6 + h7));
        }
        for (; e + 3 < end; e += 4) {
            int s0 = pack[e], s1 = pack[e + 1], s2 = pack[e + 2], s3 = pack[e + 3];
            float h0 = hs1[(size_t)s0 * 64 + lane];
            float h1 = hs1[(size_t)s1 * 64 + lane];
            float h2 = hs1[(size_t)s2 * 64 + lane];
            float h3 = hs1[(size_t)s3 * 64 + lane];
            acc += (h0 + h1) + (h2 + h3);
        }
        for (; e < end; ++e)
            acc += hs1[(size_t)pack[e] * 64 + lane];
        xs[r][lane] = fmaxf(di * (own + acc) + bb, 0.f);
    }
    __syncthreads();

    const int sub = tid >> 4;
    const int c0  = (tid & 15) * 4;
    const int n   = base + sub;
    float a0 = 0.f, a1 = 0.f, a2 = 0.f, a3 = 0.f;
#pragma unroll
    for (int k = 0; k < 64; k += 4) {
        float4 xv = *reinterpret_cast<const float4*>(&xs[sub][k]);
        float4 w0 = *reinterpret_cast<const float4*>(&ws[k][c0]);
        float4 w1 = *reinterpret_cast<const float4*>(&ws[k + 1][c0]);
        float4 w2 = *reinterpret_cast<const float4*>(&ws[k + 2][c0]);
        float4 w3 = *reinterpret_cast<const float4*>(&ws[k + 3][c0]);
        a0 += xv.x * w0.x + xv.y * w1.x + xv.z * w2.x + xv.w * w3.x;
        a1 += xv.x * w0.y + xv.y * w1.y + xv.z * w2.y + xv.w * w3.y;
        a2 += xv.x * w0.z + xv.y * w1.z + xv.z * w2.z + xv.w * w3.z;
        a3 += xv.x * w0.w + xv.y * w1.w + xv.z * w2.w + xv.w * w3.w;
    }
    float di = dinv[n];
    *reinterpret_cast<float4*>(&hs2[(size_t)n * 64 + c0]) =
        make_float4(a0 * di, a1 * di, a2 * di, a3 * di);
}

// ---------------- fused gather2 + mean-pool accumulate ----------------
__global__ __launch_bounds__(256) void gatherpool_kernel(
    const int* __restrict__ rs, const int* __restrict__ pack,
    const float* __restrict__ hs2, const float* __restrict__ dinv,
    const float* __restrict__ b2, const int* __restrict__ batch,
    float* __restrict__ pooled) {
    int wave = threadIdx.x >> 6;
    int lane = threadIdx.x & 63;
    int base = blockIdx.x * 16 + wave * 4;
    if (base >= N_NODES) return;
    int endn = base + 4;
    if (endn > N_NODES) endn = N_NODES;
    const float bb = b2[lane];
    int curg = batch[base];
    float racc = 0.f;
    for (int n = base; n < endn; ++n) {
        float own = hs2[(size_t)n * 64 + lane];
        float di  = dinv[n];
        int e = rs[n], end = rs[n + 1];
        float acc = 0.f;
        for (; e + 7 < end; e += 8) {
            int s0 = pack[e],     s1 = pack[e + 1], s2 = pack[e + 2], s3 = pack[e + 3];
            int s4 = pack[e + 4], s5 = pack[e + 5], s6 = pack[e + 6], s7 = pack[e + 7];
            float h0 = hs2[(size_t)s0 * 64 + lane];
            float h1 = hs2[(size_t)s1 * 64 + lane];
            float h2 = hs2[(size_t)s2 * 64 + lane];
            float h3 = hs2[(size_t)s3 * 64 + lane];
            float h4 = hs2[(size_t)s4 * 64 + lane];
            float h5 = hs2[(size_t)s5 * 64 + lane];
            float h6 = hs2[(size_t)s6 * 64 + lane];
            float h7 = hs2[(size_t)s7 * 64 + lane];
            acc += ((h0 + h1) + (h2 + h3)) + ((h4 + h5) + (h6 + h7));
        }
        for (; e + 3 < end; e += 4) {
            int s0 = pack[e], s1 = pack[e + 1], s2 = pack[e + 2], s3 = pack[e + 3];
            float h0 = hs2[(size_t)s0 * 64 + lane];
            float h1 = hs2[(size_t)s1 * 64 + lane];
            float h2 = hs2[(size_t)s2 * 64 + lane];
            float h3 = hs2[(size_t)s3 * 64 + lane];
            acc += (h0 + h1) + (h2 + h3);
        }
        for (; e < end; ++e)
            acc += hs2[(size_t)pack[e] * 64 + lane];
        float val = di * (own + acc) + bb;
        int g = batch[n];
        if (g != curg) {
            atomicAdd(&pooled[curg * 64 + lane], racc);
            racc = 0.f;
            curg = g;
        }
        racc += val;
    }
    atomicAdd(&pooled[curg * 64 + lane], racc);
}

// ---------------- head: (pooled/count) @ Wl + bl ----------------
__global__ __launch_bounds__(256) void head_kernel(const float* __restrict__ pooled,
                                                   const int* __restrict__ start,
                                                   const float* __restrict__ Wl,
                                                   const float* __restrict__ bl,
                                                   float* __restrict__ out) {
    int gid = blockIdx.x * 256 + threadIdx.x;
    if (gid >= N_GRAPHS * N_CLASSES) return;
    int g = gid / N_CLASSES, c = gid % N_CLASSES;
    float cntf = (float)(start[g + 1] - start[g]);
    float inv = 1.0f / fmaxf(cntf, 1.0f);
    float acc = 0.f;
#pragma unroll
    for (int k = 0; k < OUT_CH; ++k)
        acc += pooled[g * 64 + k] * Wl[k * N_CLASSES + c];
    out[gid] = acc * inv + bl[c];
}

// ---------------- launch ----------------
extern "C" void kernel_launch(void* const* d_in, const int* in_sizes, int n_in,
                              void* d_out, int out_size, void* d_ws, size_t ws_size,
                              hipStream_t stream) {
    const float* x     = (const float*)d_in[0];
    const int*   ei    = (const int*)d_in[1];
    const int*   batch = (const int*)d_in[3];
    const float* W1    = (const float*)d_in[4];
    const float* b1    = (const float*)d_in[5];
    const float* W2    = (const float*)d_in[6];
    const float* b2    = (const float*)d_in[7];
    const float* Wl    = (const float*)d_in[8];
    const float* bl    = (const float*)d_in[9];
    float* out = (float*)d_out;

    // workspace layout (4-byte units)
    int*   wsI    = (int*)d_ws;
    int*   cnt    = wsI;                         // [0, 50048)  zeroed
    float* pooled = (float*)(wsI + 50048);       // [50048, 66432) zeroed
    int*   start  = wsI + 66432;                 // [66432, 66689)
    float* dinv   = (float*)(wsI + 66752);       // [66752, 116800)
    int*   excl   = wsI + 116800;                // [116800, 166848)
    int*   part   = wsI + 166848;                // [166848, 167104)
    int*   rs     = wsI + 167104;                // [167104, 217168) N_NODES+1
    int*   cur    = wsI + 217168;                // [217168, 267216)
    int*   pack   = wsI + 267216;                // [267216, 1067216) 800000 ints
    float* hs1    = (float*)(wsI + 1067216);     // 3.2M floats
    float* hs2    = (float*)(wsI + 4267216);     // 3.2M floats

    const int NBLK = (N_NODES + 255) / 256;      // 196

    // zero cnt + pooled
    hipMemsetAsync(wsI, 0, (size_t)66432 * sizeof(int), stream);

    // degree + CSR build (same work every call)
    deg_kernel   <<<(N_EDGES + 255) / 256, 256, 0, stream>>>(ei, cnt);
    scan1_kernel <<<NBLK, 256, 0, stream>>>(cnt, excl, part);
    scan3_kernel <<<NBLK, 256, 0, stream>>>(excl, part, cnt, batch,
                                            rs, cur, dinv, start, NBLK);
    bucket_kernel<<<(N_EDGES + 255) / 256, 256, 0, stream>>>(ei, cur, pack);

    // layer 1 GEMM (hs1 = x@W1 * dinv)   [50000 = 3125 * 16 exactly]
    gemm1_kernel<<<N_NODES / 16, 256, 0, stream>>>(x, W1, dinv, hs1);

    // layer 1 gather fused into layer 2 GEMM (hs2 = relu(agg1)@W2 * dinv)
    gemmgather2_kernel<<<N_NODES / 16, 256, 0, stream>>>(
        rs, pack, hs1, dinv, W2, b1, hs2);

    // layer 2 gather fused with mean-pool accumulation (4 nodes/wave)
    gatherpool_kernel<<<(N_NODES + 15) / 16, 256, 0, stream>>>(
        rs, pack, hs2, dinv, b2, batch, pooled);

    // head
    head_kernel<<<(N_GRAPHS * N_CLASSES + 255) / 256, 256, 0, stream>>>(
        pooled, start, Wl, bl, out);
}